// Round 2
// baseline (342.423 us; speedup 1.0000x reference)
//
#include <hip/hip_runtime.h>
#include <stdint.h>

#define NODES 16384
#define D0    263
#define K1PAD 288
#define OUTW  1031   // 263 + 256*3

typedef __attribute__((ext_vector_type(8))) short bf16x8;
typedef __attribute__((ext_vector_type(4))) float f32x4;

__device__ __forceinline__ float bf2f(unsigned short u) {
    union { unsigned int i; float f; } c; c.i = ((unsigned int)u) << 16; return c.f;
}
__device__ __forceinline__ unsigned short f2bf(float f) {
    union { float f; unsigned int i; } c; c.f = f;
    unsigned int x = c.i;
    unsigned int r = (x + 0x7fffu + ((x >> 16) & 1u)) >> 16;
    return (unsigned short)r;
}

// ------------------------------------------------------------- dtype detect
// flags[0]: edge_index is int64 (else int32)
// flags[1]: float tensors are f32 (else bf16)
__global__ void detect_kernel(const void* __restrict__ ei, const void* __restrict__ pooled,
                              int* __restrict__ flags) {
    int lane = threadIdx.x;
    // edge width: valid node ids only if read at the true width
    const long long* e64 = (const long long*)ei;
    bool ok = true;
    for (int i = lane; i < 512; i += 64) {
        long long v = e64[i];
        if (v < 0 || v >= NODES) ok = false;
    }
    unsigned long long b = __ballot(ok);
    // float width: f32 low-halfwords have uniform-random exponent fields
    const unsigned short* ph = (const unsigned short*)pooled;
    int hits = 0;
    for (int i = lane; i < 512; i += 64) {
        int e = (ph[i] >> 7) & 0xFF;
        if (e >= 0x90) hits++;   // |v| >= 2^17: impossible for N(0,1) bf16 data
    }
    for (int off = 32; off; off >>= 1) hits += __shfl_down(hits, off);
    if (lane == 0) {
        flags[0] = (b == ~0ull) ? 1 : 0;
        flags[1] = (hits > 8) ? 1 : 0;
    }
}

__global__ void convert_kernel(const void* __restrict__ ei, int E, const int* __restrict__ flags,
                               int* __restrict__ src, int* __restrict__ dst) {
    int e = blockIdx.x * blockDim.x + threadIdx.x;
    if (e >= E) return;
    if (flags[0]) {
        const long long* p = (const long long*)ei;
        src[e] = (int)p[e];
        dst[e] = (int)p[(size_t)E + e];
    } else {
        const int* p = (const int*)ei;
        src[e] = p[e];
        dst[e] = p[(size_t)E + e];
    }
}

// ---------------------------------------------------------------- edge sort
__global__ void hist_kernel(const int* __restrict__ dst, int E, int* __restrict__ deg) {
    int e = blockIdx.x * blockDim.x + threadIdx.x;
    if (e < E) atomicAdd(&deg[dst[e]], 1);
}

__global__ void scan_kernel(const int* __restrict__ deg, int* __restrict__ offs,
                            int* __restrict__ cursor) {
    __shared__ int part[256];
    int tid = threadIdx.x;
    int base = tid * 64;
    int s = 0;
    for (int i = 0; i < 64; ++i) s += deg[base + i];
    part[tid] = s;
    __syncthreads();
    for (int off = 1; off < 256; off <<= 1) {
        int t = (tid >= off) ? part[tid - off] : 0;
        __syncthreads();
        part[tid] += t;
        __syncthreads();
    }
    int run = (tid > 0) ? part[tid - 1] : 0;
    for (int i = 0; i < 64; ++i) {
        int idx = base + i;
        offs[idx] = run;
        cursor[idx] = run;
        run += deg[idx];
    }
    if (tid == 255) offs[NODES] = run;
}

__global__ void scatter_kernel(const int* __restrict__ src, const int* __restrict__ dst, int E,
                               int* __restrict__ cursor, int* __restrict__ ssrc) {
    int e = blockIdx.x * blockDim.x + threadIdx.x;
    if (e >= E) return;
    int i = dst[e];
    int pos = atomicAdd(&cursor[i], 1);
    ssrc[pos] = src[e];
}

// ---------------------------------------------------------------- features
__global__ void build_x0_kernel(const void* __restrict__ pooled, const void* __restrict__ rois,
                                const int* __restrict__ flags,
                                unsigned short* __restrict__ x0p, void* __restrict__ outv) {
    int idx = blockIdx.x * blockDim.x + threadIdx.x;
    int node = idx / K1PAD;
    int k = idx - node * K1PAD;
    if (node >= NODES) return;
    bool f32m = flags[1] != 0;
    float val = 0.f;
    if (k < 256) {
        val = f32m ? ((const float*)pooled)[(size_t)node * 256 + k]
                   : bf2f(((const unsigned short*)pooled)[(size_t)node * 256 + k]);
    } else if (k < D0) {
        val = f32m ? ((const float*)rois)[(size_t)node * 7 + (k - 256)]
                   : bf2f(((const unsigned short*)rois)[(size_t)node * 7 + (k - 256)]);
    }
    x0p[idx] = f2bf(val);
    if (k < D0) {
        if (f32m) ((float*)outv)[(size_t)node * OUTW + k] = val;
        else      ((unsigned short*)outv)[(size_t)node * OUTW + k] = f2bf(val);
    }
}

// Wcomb = [Wa ; Wb - Wa], layer 1 (in=263 padded to 288; W1 is [256][526])
__global__ void prep_w1_kernel(const void* __restrict__ W1, const int* __restrict__ flags,
                               unsigned short* __restrict__ wc) {
    int idx = blockIdx.x * blockDim.x + threadIdx.x;
    if (idx >= 512 * K1PAD) return;
    bool f32m = flags[1] != 0;
    int r = idx / K1PAD;
    int k = idx - r * K1PAD;
    unsigned short val = 0;
    if (k < D0) {
        float a, b;
        if (r < 256) {
            a = f32m ? ((const float*)W1)[(size_t)r * 526 + k]
                     : bf2f(((const unsigned short*)W1)[(size_t)r * 526 + k]);
            val = f2bf(a);
        } else {
            size_t ro = (size_t)(r - 256) * 526;
            if (f32m) {
                a = ((const float*)W1)[ro + k];
                b = ((const float*)W1)[ro + D0 + k];
            } else {
                a = bf2f(((const unsigned short*)W1)[ro + k]);
                b = bf2f(((const unsigned short*)W1)[ro + D0 + k]);
            }
            val = f2bf(b - a);
        }
    }
    wc[idx] = val;
}

// Wcomb for layers 2/3 (in=256; W is [256][512])
__global__ void prep_w23_kernel(const void* __restrict__ W, const int* __restrict__ flags,
                                unsigned short* __restrict__ wc) {
    int idx = blockIdx.x * blockDim.x + threadIdx.x;
    if (idx >= 512 * 256) return;
    bool f32m = flags[1] != 0;
    int r = idx >> 8;
    int k = idx & 255;
    unsigned short val;
    if (r < 256) {
        float a = f32m ? ((const float*)W)[(size_t)r * 512 + k]
                       : bf2f(((const unsigned short*)W)[(size_t)r * 512 + k]);
        val = f2bf(a);
    } else {
        size_t ro = (size_t)(r - 256) * 512;
        float a, b;
        if (f32m) { a = ((const float*)W)[ro + k]; b = ((const float*)W)[ro + 256 + k]; }
        else      { a = bf2f(((const unsigned short*)W)[ro + k]);
                    b = bf2f(((const unsigned short*)W)[ro + 256 + k]); }
        val = f2bf(b - a);
    }
    wc[idx] = val;
}

// ---------------------------------------------------------------- GEMM
// T[M,512] = A[M,K] * Wc[512,K]^T ; cols 0..255 -> u (bf16), 256..511 -> v (f32)
template <int K>
__global__ __launch_bounds__(256) void gemm_kernel(const unsigned short* __restrict__ A,
                                                   const unsigned short* __restrict__ Wc,
                                                   unsigned short* __restrict__ u_bf,
                                                   float* __restrict__ v_f) {
    int lane = threadIdx.x & 63;
    int wave = threadIdx.x >> 6;
    int row0 = blockIdx.x * 64 + wave * 16;
    int col0 = blockIdx.y * 64;
    int lr = lane & 15;
    int kb = (lane >> 4) * 8;
    const unsigned short* Ap = A + (size_t)(row0 + lr) * K + kb;
    const unsigned short* Wp = Wc + (size_t)(col0 + lr) * K + kb;

    f32x4 acc[4];
    #pragma unroll
    for (int nb = 0; nb < 4; ++nb) acc[nb] = (f32x4){0.f, 0.f, 0.f, 0.f};

    for (int k0 = 0; k0 < K; k0 += 32) {
        bf16x8 a = *reinterpret_cast<const bf16x8*>(Ap + k0);
        #pragma unroll
        for (int nb = 0; nb < 4; ++nb) {
            bf16x8 b = *reinterpret_cast<const bf16x8*>(Wp + (size_t)nb * 16 * K + k0);
            acc[nb] = __builtin_amdgcn_mfma_f32_16x16x32_bf16(a, b, acc[nb], 0, 0, 0);
        }
    }

    int rbase = row0 + (lane >> 4) * 4;
    bool is_u = (col0 < 256);
    #pragma unroll
    for (int nb = 0; nb < 4; ++nb) {
        int c = col0 + nb * 16 + lr;
        #pragma unroll
        for (int reg = 0; reg < 4; ++reg) {
            int r = rbase + reg;
            float val = acc[nb][reg];
            if (is_u) u_bf[(size_t)r * 256 + c] = f2bf(val);
            else      v_f[(size_t)r * 256 + (c - 256)] = val;
        }
    }
}

// ---------------------------------------------------------------- combine
// one wave per node: m[c] = max over sorted sources of u[src][c];
// x_next = deg>0 ? relu(m + v + b) : 0 ; write bf16 x_cur and out slice (dtype per flag)
__global__ __launch_bounds__(256) void combine_kernel(const unsigned short* __restrict__ u_bf,
                                                      const float* __restrict__ v_f,
                                                      const void* __restrict__ bias,
                                                      const int* __restrict__ flags,
                                                      const int* __restrict__ offs,
                                                      const int* __restrict__ ssrc,
                                                      unsigned short* __restrict__ x_cur,
                                                      void* __restrict__ outv,
                                                      int col_off) {
    int lane = threadIdx.x & 63;
    int node = blockIdx.x * 4 + (threadIdx.x >> 6);
    int s0 = offs[node];
    int s1 = offs[node + 1];
    bool f32m = flags[1] != 0;

    float m0 = -INFINITY, m1 = -INFINITY, m2 = -INFINITY, m3 = -INFINITY;
    const uint2* ubase = (const uint2*)u_bf;  // one row = 64 uint2 (256 bf16)

    for (int base = s0; base < s1; base += 64) {
        int n = min(64, s1 - base);
        int myidx = (base + lane < s1) ? ssrc[base + lane] : 0;
        for (int j = 0; j < n; ++j) {
            int s = __shfl(myidx, j);
            uint2 p = ubase[(size_t)s * 64 + lane];
            m0 = fmaxf(m0, bf2f((unsigned short)(p.x & 0xffff)));
            m1 = fmaxf(m1, bf2f((unsigned short)(p.x >> 16)));
            m2 = fmaxf(m2, bf2f((unsigned short)(p.y & 0xffff)));
            m3 = fmaxf(m3, bf2f((unsigned short)(p.y >> 16)));
        }
    }

    float4 v = *(const float4*)(v_f + (size_t)node * 256 + lane * 4);
    float b0, b1, b2, b3;
    if (f32m) {
        const float* bf = (const float*)bias;
        b0 = bf[lane * 4 + 0]; b1 = bf[lane * 4 + 1];
        b2 = bf[lane * 4 + 2]; b3 = bf[lane * 4 + 3];
    } else {
        const unsigned short* bh = (const unsigned short*)bias;
        b0 = bf2f(bh[lane * 4 + 0]); b1 = bf2f(bh[lane * 4 + 1]);
        b2 = bf2f(bh[lane * 4 + 2]); b3 = bf2f(bh[lane * 4 + 3]);
    }

    float r0, r1, r2, r3;
    if (s1 > s0) {
        r0 = fmaxf(m0 + v.x + b0, 0.f);
        r1 = fmaxf(m1 + v.y + b1, 0.f);
        r2 = fmaxf(m2 + v.z + b2, 0.f);
        r3 = fmaxf(m3 + v.w + b3, 0.f);
    } else {
        r0 = r1 = r2 = r3 = 0.f;
    }

    unsigned short h0 = f2bf(r0), h1 = f2bf(r1), h2 = f2bf(r2), h3 = f2bf(r3);
    uint2 packed;
    packed.x = (unsigned int)h0 | ((unsigned int)h1 << 16);
    packed.y = (unsigned int)h2 | ((unsigned int)h3 << 16);
    *(uint2*)(x_cur + (size_t)node * 256 + lane * 4) = packed;

    if (f32m) {
        float* of = (float*)outv;
        size_t ob = (size_t)node * OUTW + col_off + lane * 4;
        of[ob + 0] = r0; of[ob + 1] = r1; of[ob + 2] = r2; of[ob + 3] = r3;
    } else {
        unsigned short* oh = (unsigned short*)outv;
        size_t ob = (size_t)node * OUTW + col_off + lane * 4;
        oh[ob + 0] = h0; oh[ob + 1] = h1; oh[ob + 2] = h2; oh[ob + 3] = h3;
    }
}

// ---------------------------------------------------------------- launch
extern "C" void kernel_launch(void* const* d_in, const int* in_sizes, int n_in,
                              void* d_out, int out_size, void* d_ws, size_t ws_size,
                              hipStream_t stream) {
    const void* rois   = d_in[0];
    const void* pooled = d_in[1];
    const void* ei     = d_in[2];
    const void* W1 = d_in[3];
    const void* b1 = d_in[4];
    const void* W2 = d_in[5];
    const void* b2 = d_in[6];
    const void* W3 = d_in[7];
    const void* b3 = d_in[8];

    const int E = in_sizes[2] / 2;

    char* ws = (char*)d_ws;
    size_t o = 0;
    auto take = [&](size_t bytes) { size_t cur = o; o += (bytes + 255) & ~(size_t)255; return cur; };
    int* flags           = (int*)(ws + take(8));
    int* esrc            = (int*)(ws + take(sizeof(int) * (size_t)E));
    int* edst            = (int*)(ws + take(sizeof(int) * (size_t)E));
    int* deg             = (int*)(ws + take(sizeof(int) * NODES));
    int* offs            = (int*)(ws + take(sizeof(int) * (NODES + 1)));
    int* cursor          = (int*)(ws + take(sizeof(int) * NODES));
    int* ssrc            = (int*)(ws + take(sizeof(int) * (size_t)E));
    unsigned short* x0p  = (unsigned short*)(ws + take(2ull * NODES * K1PAD));
    unsigned short* wc   = (unsigned short*)(ws + take(2ull * 512 * K1PAD));
    unsigned short* ubf  = (unsigned short*)(ws + take(2ull * NODES * 256));
    float*          vf   = (float*)(ws + take(4ull * NODES * 256));
    unsigned short* xcur = (unsigned short*)(ws + take(2ull * NODES * 256));
    (void)ws_size;

    const int eb = (E + 255) / 256;

    detect_kernel<<<1, 64, 0, stream>>>(ei, pooled, flags);
    convert_kernel<<<eb, 256, 0, stream>>>(ei, E, flags, esrc, edst);
    hipMemsetAsync(deg, 0, sizeof(int) * NODES, stream);
    hist_kernel<<<eb, 256, 0, stream>>>(edst, E, deg);
    scan_kernel<<<1, 256, 0, stream>>>(deg, offs, cursor);
    scatter_kernel<<<eb, 256, 0, stream>>>(esrc, edst, E, cursor, ssrc);

    build_x0_kernel<<<(NODES * K1PAD) / 256, 256, 0, stream>>>(pooled, rois, flags, x0p, d_out);

    // layer 1
    prep_w1_kernel<<<(512 * K1PAD + 255) / 256, 256, 0, stream>>>(W1, flags, wc);
    gemm_kernel<K1PAD><<<dim3(NODES / 64, 8), 256, 0, stream>>>(x0p, wc, ubf, vf);
    combine_kernel<<<NODES / 4, 256, 0, stream>>>(ubf, vf, b1, flags, offs, ssrc, xcur, d_out, D0);

    // layer 2
    prep_w23_kernel<<<(512 * 256) / 256, 256, 0, stream>>>(W2, flags, wc);
    gemm_kernel<256><<<dim3(NODES / 64, 8), 256, 0, stream>>>(xcur, wc, ubf, vf);
    combine_kernel<<<NODES / 4, 256, 0, stream>>>(ubf, vf, b2, flags, offs, ssrc, xcur, d_out, D0 + 256);

    // layer 3
    prep_w23_kernel<<<(512 * 256) / 256, 256, 0, stream>>>(W3, flags, wc);
    gemm_kernel<256><<<dim3(NODES / 64, 8), 256, 0, stream>>>(xcur, wc, ubf, vf);
    combine_kernel<<<NODES / 4, 256, 0, stream>>>(ubf, vf, b3, flags, offs, ssrc, xcur, d_out, D0 + 512);
}

// Round 3
// 258.255 us; speedup vs baseline: 1.3259x; 1.3259x over previous
//
#include <hip/hip_runtime.h>
#include <stdint.h>

#define NODES 16384
#define D0    263
#define K1PAD 288
#define OUTW  1031   // 263 + 256*3

typedef __attribute__((ext_vector_type(8))) short bf16x8;
typedef __attribute__((ext_vector_type(4))) float f32x4;

__device__ __forceinline__ float bf2f(unsigned short u) {
    union { unsigned int i; float f; } c; c.i = ((unsigned int)u) << 16; return c.f;
}
__device__ __forceinline__ unsigned short f2bf(float f) {
    union { float f; unsigned int i; } c; c.f = f;
    unsigned int x = c.i;
    unsigned int r = (x + 0x7fffu + ((x >> 16) & 1u)) >> 16;
    return (unsigned short)r;
}

// ------------------------------------------------------------- dtype detect
// flags[0]: edge_index is int64 (else int32)
// flags[1]: float tensors are f32 (else bf16)
__global__ void detect_kernel(const void* __restrict__ ei, const void* __restrict__ pooled,
                              int* __restrict__ flags) {
    int lane = threadIdx.x;
    const long long* e64 = (const long long*)ei;
    bool ok = true;
    for (int i = lane; i < 512; i += 64) {
        long long v = e64[i];
        if (v < 0 || v >= NODES) ok = false;
    }
    unsigned long long b = __ballot(ok);
    const unsigned short* ph = (const unsigned short*)pooled;
    int hits = 0;
    for (int i = lane; i < 512; i += 64) {
        int e = (ph[i] >> 7) & 0xFF;
        if (e >= 0x90) hits++;   // |v| >= 2^17: impossible for N(0,1) bf16 data
    }
    for (int off = 32; off; off >>= 1) hits += __shfl_down(hits, off);
    if (lane == 0) {
        flags[0] = (b == ~0ull) ? 1 : 0;
        flags[1] = (hits > 8) ? 1 : 0;
    }
}

// ---------------------------------------------------------------- edge sort
__global__ void hist_kernel(const void* __restrict__ ei, int E, const int* __restrict__ flags,
                            int* __restrict__ deg) {
    int e = blockIdx.x * blockDim.x + threadIdx.x;
    if (e >= E) return;
    int d = flags[0] ? (int)((const long long*)ei)[(size_t)E + e]
                     : ((const int*)ei)[(size_t)E + e];
    atomicAdd(&deg[d], 1);
}

__global__ void scan_kernel(const int* __restrict__ deg, int* __restrict__ offs,
                            int* __restrict__ cursor) {
    __shared__ int part[256];
    int tid = threadIdx.x;
    int base = tid * 64;
    int s = 0;
    for (int i = 0; i < 64; ++i) s += deg[base + i];
    part[tid] = s;
    __syncthreads();
    for (int off = 1; off < 256; off <<= 1) {
        int t = (tid >= off) ? part[tid - off] : 0;
        __syncthreads();
        part[tid] += t;
        __syncthreads();
    }
    int run = (tid > 0) ? part[tid - 1] : 0;
    for (int i = 0; i < 64; ++i) {
        int idx = base + i;
        offs[idx] = run;
        cursor[idx] = run;
        run += deg[idx];
    }
    if (tid == 255) offs[NODES] = run;
}

__global__ void scatter_kernel(const void* __restrict__ ei, int E, const int* __restrict__ flags,
                               int* __restrict__ cursor, int* __restrict__ ssrc) {
    int e = blockIdx.x * blockDim.x + threadIdx.x;
    if (e >= E) return;
    int s, d;
    if (flags[0]) {
        const long long* p = (const long long*)ei;
        s = (int)p[e];
        d = (int)p[(size_t)E + e];
    } else {
        const int* p = (const int*)ei;
        s = p[e];
        d = p[(size_t)E + e];
    }
    int pos = atomicAdd(&cursor[d], 1);
    ssrc[pos] = s;
}

// ---------------------------------------------------------------- features
__global__ void build_x0_kernel(const void* __restrict__ pooled, const void* __restrict__ rois,
                                const int* __restrict__ flags,
                                unsigned short* __restrict__ x0p, void* __restrict__ outv) {
    int idx = blockIdx.x * blockDim.x + threadIdx.x;
    int node = idx / K1PAD;
    int k = idx - node * K1PAD;
    if (node >= NODES) return;
    bool f32m = flags[1] != 0;
    float val = 0.f;
    if (k < 256) {
        val = f32m ? ((const float*)pooled)[(size_t)node * 256 + k]
                   : bf2f(((const unsigned short*)pooled)[(size_t)node * 256 + k]);
    } else if (k < D0) {
        val = f32m ? ((const float*)rois)[(size_t)node * 7 + (k - 256)]
                   : bf2f(((const unsigned short*)rois)[(size_t)node * 7 + (k - 256)]);
    }
    x0p[idx] = f2bf(val);
    if (k < D0) {
        if (f32m) ((float*)outv)[(size_t)node * OUTW + k] = val;
        else      ((unsigned short*)outv)[(size_t)node * OUTW + k] = f2bf(val);
    }
}

// Wcomb = [Wa ; Wb - Wa] for all three layers in one dispatch.
#define S1 (512 * K1PAD)
#define S2 (512 * 256)
__global__ void prep_all_kernel(const void* __restrict__ W1, const void* __restrict__ W2,
                                const void* __restrict__ W3, const int* __restrict__ flags,
                                unsigned short* __restrict__ wc1,
                                unsigned short* __restrict__ wc2,
                                unsigned short* __restrict__ wc3) {
    int idx = blockIdx.x * blockDim.x + threadIdx.x;
    bool f32m = flags[1] != 0;
    if (idx < S1) {
        // layer 1: W1 is [256][526], in=263 padded to 288
        int r = idx / K1PAD;
        int k = idx - r * K1PAD;
        unsigned short val = 0;
        if (k < D0) {
            if (r < 256) {
                float a = f32m ? ((const float*)W1)[(size_t)r * 526 + k]
                               : bf2f(((const unsigned short*)W1)[(size_t)r * 526 + k]);
                val = f2bf(a);
            } else {
                size_t ro = (size_t)(r - 256) * 526;
                float a, b;
                if (f32m) { a = ((const float*)W1)[ro + k]; b = ((const float*)W1)[ro + D0 + k]; }
                else      { a = bf2f(((const unsigned short*)W1)[ro + k]);
                            b = bf2f(((const unsigned short*)W1)[ro + D0 + k]); }
                val = f2bf(b - a);
            }
        }
        wc1[idx] = val;
        return;
    }
    idx -= S1;
    const void* W = (idx < S2) ? W2 : W3;
    unsigned short* wc = (idx < S2) ? wc2 : wc3;
    if (idx >= S2) idx -= S2;
    if (idx >= S2) return;
    int r = idx >> 8;
    int k = idx & 255;
    unsigned short val;
    if (r < 256) {
        float a = f32m ? ((const float*)W)[(size_t)r * 512 + k]
                       : bf2f(((const unsigned short*)W)[(size_t)r * 512 + k]);
        val = f2bf(a);
    } else {
        size_t ro = (size_t)(r - 256) * 512;
        float a, b;
        if (f32m) { a = ((const float*)W)[ro + k]; b = ((const float*)W)[ro + 256 + k]; }
        else      { a = bf2f(((const unsigned short*)W)[ro + k]);
                    b = bf2f(((const unsigned short*)W)[ro + 256 + k]); }
        val = f2bf(b - a);
    }
    wc[idx] = val;
}

// ---------------------------------------------------------------- GEMM
// T[M,512] = A[M,K] * Wc[512,K]^T ; cols 0..255 -> u (bf16), 256..511 -> v (f32)
// wave computes 64 rows x 64 cols (acc[4][4]); block = 4 waves = 64 rows x 256 cols.
// grid (NODES/64, 2): blockIdx.y==0 -> u halves, ==1 -> v half.
template <int K>
__global__ __launch_bounds__(256) void gemm_kernel(const unsigned short* __restrict__ A,
                                                   const unsigned short* __restrict__ Wc,
                                                   unsigned short* __restrict__ u_bf,
                                                   float* __restrict__ v_f) {
    int lane = threadIdx.x & 63;
    int wave = threadIdx.x >> 6;
    int row0 = blockIdx.x * 64;
    int col0 = blockIdx.y * 256 + wave * 64;
    int lr = lane & 15;
    int kb = (lane >> 4) * 8;
    const unsigned short* Ap = A + (size_t)(row0 + lr) * K + kb;
    const unsigned short* Wp = Wc + (size_t)(col0 + lr) * K + kb;

    f32x4 acc[4][4];
    #pragma unroll
    for (int i = 0; i < 4; ++i)
        #pragma unroll
        for (int j = 0; j < 4; ++j) acc[i][j] = (f32x4){0.f, 0.f, 0.f, 0.f};

    for (int k0 = 0; k0 < K; k0 += 32) {
        bf16x8 a[4], b[4];
        #pragma unroll
        for (int i = 0; i < 4; ++i) a[i] = *reinterpret_cast<const bf16x8*>(Ap + (size_t)i * 16 * K + k0);
        #pragma unroll
        for (int i = 0; i < 4; ++i) b[i] = *reinterpret_cast<const bf16x8*>(Wp + (size_t)i * 16 * K + k0);
        #pragma unroll
        for (int rb = 0; rb < 4; ++rb)
            #pragma unroll
            for (int cb = 0; cb < 4; ++cb)
                acc[rb][cb] = __builtin_amdgcn_mfma_f32_16x16x32_bf16(a[rb], b[cb], acc[rb][cb], 0, 0, 0);
    }

    bool is_u = (blockIdx.y == 0);
    #pragma unroll
    for (int rb = 0; rb < 4; ++rb) {
        int rbase = row0 + rb * 16 + (lane >> 4) * 4;
        #pragma unroll
        for (int cb = 0; cb < 4; ++cb) {
            int c = col0 + cb * 16 + lr;
            #pragma unroll
            for (int reg = 0; reg < 4; ++reg) {
                float val = acc[rb][cb][reg];
                int r = rbase + reg;
                if (is_u) u_bf[(size_t)r * 256 + c] = f2bf(val);
                else      v_f[(size_t)r * 256 + (c - 256)] = val;
            }
        }
    }
}

// ---------------------------------------------------------------- combine
// one wave per node; two 32-lane halves each own alternate sorted rows with
// uint4 (8 bf16-ch) loads, 4 rows/half in flight; cross-half shfl_xor merge.
__device__ __forceinline__ void maxpack2(float m[8], uint4 p, uint4 q) {
    unsigned pp[4] = {p.x, p.y, p.z, p.w};
    unsigned qq[4] = {q.x, q.y, q.z, q.w};
    #pragma unroll
    for (int w = 0; w < 4; ++w) {
        m[2 * w]     = fmaxf(fmaxf(m[2 * w],     bf2f((unsigned short)(pp[w] & 0xffff))),
                             bf2f((unsigned short)(qq[w] & 0xffff)));
        m[2 * w + 1] = fmaxf(fmaxf(m[2 * w + 1], bf2f((unsigned short)(pp[w] >> 16))),
                             bf2f((unsigned short)(qq[w] >> 16)));
    }
}
__device__ __forceinline__ void maxpack1(float m[8], uint4 p) {
    unsigned pp[4] = {p.x, p.y, p.z, p.w};
    #pragma unroll
    for (int w = 0; w < 4; ++w) {
        m[2 * w]     = fmaxf(m[2 * w],     bf2f((unsigned short)(pp[w] & 0xffff)));
        m[2 * w + 1] = fmaxf(m[2 * w + 1], bf2f((unsigned short)(pp[w] >> 16)));
    }
}

__global__ __launch_bounds__(256) void combine_kernel(const unsigned short* __restrict__ u_bf,
                                                      const float* __restrict__ v_f,
                                                      const void* __restrict__ bias,
                                                      const int* __restrict__ flags,
                                                      const int* __restrict__ offs,
                                                      const int* __restrict__ ssrc,
                                                      unsigned short* __restrict__ x_cur,
                                                      void* __restrict__ outv,
                                                      int col_off) {
    int lane = threadIdx.x & 63;
    int node = blockIdx.x * 4 + (threadIdx.x >> 6);
    int half = lane >> 5;      // 0/1: alternate rows
    int cl = lane & 31;        // channel-lane: ch cl*8 .. cl*8+7
    int s0 = offs[node];
    int s1 = offs[node + 1];
    bool f32m = flags[1] != 0;

    const uint4* U = (const uint4*)u_bf;   // one row = 32 uint4
    float m[8];
    #pragma unroll
    for (int j = 0; j < 8; ++j) m[j] = -INFINITY;

    int i = s0 + half;
    for (; i + 6 < s1; i += 8) {
        int sA = ssrc[i], sB = ssrc[i + 2], sC = ssrc[i + 4], sD = ssrc[i + 6];
        uint4 pA = U[(size_t)sA * 32 + cl];
        uint4 pB = U[(size_t)sB * 32 + cl];
        uint4 pC = U[(size_t)sC * 32 + cl];
        uint4 pD = U[(size_t)sD * 32 + cl];
        maxpack2(m, pA, pB);
        maxpack2(m, pC, pD);
    }
    for (; i < s1; i += 2) {
        int s = ssrc[i];
        maxpack1(m, U[(size_t)s * 32 + cl]);
    }

    // merge halves: lanes l and l^32 hold same channel group
    #pragma unroll
    for (int j = 0; j < 8; ++j) m[j] = fmaxf(m[j], __shfl_xor(m[j], 32));

    // epilogue: lane handles 4 channels: ch0 = cl*8 + half*4
    int ch0 = cl * 8 + half * 4;
    float mm[4] = {m[half * 4 + 0], m[half * 4 + 1], m[half * 4 + 2], m[half * 4 + 3]};
    float4 v = *(const float4*)(v_f + (size_t)node * 256 + ch0);
    float bb[4];
    if (f32m) {
        const float* bf = (const float*)bias;
        #pragma unroll
        for (int j = 0; j < 4; ++j) bb[j] = bf[ch0 + j];
    } else {
        const unsigned short* bh = (const unsigned short*)bias;
        #pragma unroll
        for (int j = 0; j < 4; ++j) bb[j] = bf2f(bh[ch0 + j]);
    }
    float vv[4] = {v.x, v.y, v.z, v.w};
    float r[4];
    bool nz = (s1 > s0);
    #pragma unroll
    for (int j = 0; j < 4; ++j) r[j] = nz ? fmaxf(mm[j] + vv[j] + bb[j], 0.f) : 0.f;

    unsigned short h[4];
    #pragma unroll
    for (int j = 0; j < 4; ++j) h[j] = f2bf(r[j]);
    uint2 packed;
    packed.x = (unsigned int)h[0] | ((unsigned int)h[1] << 16);
    packed.y = (unsigned int)h[2] | ((unsigned int)h[3] << 16);
    *(uint2*)(x_cur + (size_t)node * 256 + ch0) = packed;

    size_t ob = (size_t)node * OUTW + col_off + ch0;
    if (f32m) {
        float* of = (float*)outv;
        #pragma unroll
        for (int j = 0; j < 4; ++j) of[ob + j] = r[j];
    } else {
        unsigned short* oh = (unsigned short*)outv;
        #pragma unroll
        for (int j = 0; j < 4; ++j) oh[ob + j] = h[j];
    }
}

// ---------------------------------------------------------------- launch
extern "C" void kernel_launch(void* const* d_in, const int* in_sizes, int n_in,
                              void* d_out, int out_size, void* d_ws, size_t ws_size,
                              hipStream_t stream) {
    const void* rois   = d_in[0];
    const void* pooled = d_in[1];
    const void* ei     = d_in[2];
    const void* W1 = d_in[3];
    const void* b1 = d_in[4];
    const void* W2 = d_in[5];
    const void* b2 = d_in[6];
    const void* W3 = d_in[7];
    const void* b3 = d_in[8];

    const int E = in_sizes[2] / 2;

    char* ws = (char*)d_ws;
    size_t o = 0;
    auto take = [&](size_t bytes) { size_t cur = o; o += (bytes + 255) & ~(size_t)255; return cur; };
    int* flags           = (int*)(ws + take(8));
    int* deg             = (int*)(ws + take(sizeof(int) * NODES));
    int* offs            = (int*)(ws + take(sizeof(int) * (NODES + 1)));
    int* cursor          = (int*)(ws + take(sizeof(int) * NODES));
    int* ssrc            = (int*)(ws + take(sizeof(int) * (size_t)E));
    unsigned short* x0p  = (unsigned short*)(ws + take(2ull * NODES * K1PAD));
    unsigned short* wc1  = (unsigned short*)(ws + take(2ull * 512 * K1PAD));
    unsigned short* wc2  = (unsigned short*)(ws + take(2ull * 512 * 256));
    unsigned short* wc3  = (unsigned short*)(ws + take(2ull * 512 * 256));
    unsigned short* ubf  = (unsigned short*)(ws + take(2ull * NODES * 256));
    float*          vf   = (float*)(ws + take(4ull * NODES * 256));
    unsigned short* xcur = (unsigned short*)(ws + take(2ull * NODES * 256));
    (void)ws_size;

    const int eb = (E + 255) / 256;

    detect_kernel<<<1, 64, 0, stream>>>(ei, pooled, flags);
    hipMemsetAsync(deg, 0, sizeof(int) * NODES, stream);
    hist_kernel<<<eb, 256, 0, stream>>>(ei, E, flags, deg);
    scan_kernel<<<1, 256, 0, stream>>>(deg, offs, cursor);
    scatter_kernel<<<eb, 256, 0, stream>>>(ei, E, flags, cursor, ssrc);

    build_x0_kernel<<<(NODES * K1PAD) / 256, 256, 0, stream>>>(pooled, rois, flags, x0p, d_out);
    prep_all_kernel<<<(S1 + 2 * S2 + 255) / 256, 256, 0, stream>>>(W1, W2, W3, flags, wc1, wc2, wc3);

    // layer 1
    gemm_kernel<K1PAD><<<dim3(NODES / 64, 2), 256, 0, stream>>>(x0p, wc1, ubf, vf);
    combine_kernel<<<NODES / 4, 256, 0, stream>>>(ubf, vf, b1, flags, offs, ssrc, xcur, d_out, D0);

    // layer 2
    gemm_kernel<256><<<dim3(NODES / 64, 2), 256, 0, stream>>>(xcur, wc2, ubf, vf);
    combine_kernel<<<NODES / 4, 256, 0, stream>>>(ubf, vf, b2, flags, offs, ssrc, xcur, d_out, D0 + 256);

    // layer 3
    gemm_kernel<256><<<dim3(NODES / 64, 2), 256, 0, stream>>>(xcur, wc3, ubf, vf);
    combine_kernel<<<NODES / 4, 256, 0, stream>>>(ubf, vf, b3, flags, offs, ssrc, xcur, d_out, D0 + 512);
}

// Round 4
// 252.703 us; speedup vs baseline: 1.3550x; 1.0220x over previous
//
#include <hip/hip_runtime.h>
#include <stdint.h>

#define NODES 16384
#define D0    263
#define K1PAD 288
#define OUTW  1031   // 263 + 256*3

typedef __attribute__((ext_vector_type(8))) short bf16x8;
typedef __attribute__((ext_vector_type(4))) float f32x4;
typedef __attribute__((ext_vector_type(8))) unsigned short u16x8;

__device__ __forceinline__ float bf2f(unsigned short u) {
    union { unsigned int i; float f; } c; c.i = ((unsigned int)u) << 16; return c.f;
}
__device__ __forceinline__ unsigned short f2bf(float f) {
    union { float f; unsigned int i; } c; c.f = f;
    unsigned int x = c.i;
    unsigned int r = (x + 0x7fffu + ((x >> 16) & 1u)) >> 16;
    return (unsigned short)r;
}
// order-preserving bf16 -> u16 key (unsigned max == float max)
__device__ __forceinline__ unsigned short bf2key(unsigned short b) {
    return (b & 0x8000u) ? (unsigned short)~b : (unsigned short)(b | 0x8000u);
}
__device__ __forceinline__ unsigned short key2bf(unsigned short k) {
    return (k & 0x8000u) ? (unsigned short)(k ^ 0x8000u) : (unsigned short)~k;
}

// ------------------------------------------------- detect dtypes + zero deg
// flags[0]: edge_index is int64 ; flags[1]: floats are f32
__global__ void detect_zero_kernel(const void* __restrict__ ei, const void* __restrict__ pooled,
                                   int* __restrict__ flags, int* __restrict__ deg) {
    int idx = blockIdx.x * 256 + threadIdx.x;
    deg[idx] = 0;
    if (blockIdx.x == 0 && threadIdx.x < 64) {
        int lane = threadIdx.x;
        const long long* e64 = (const long long*)ei;
        bool ok = true;
        for (int i = lane; i < 512; i += 64) {
            long long v = e64[i];
            if (v < 0 || v >= NODES) ok = false;
        }
        unsigned long long b = __ballot(ok);
        const unsigned short* ph = (const unsigned short*)pooled;
        int hits = 0;
        for (int i = lane; i < 512; i += 64) {
            int e = (ph[i] >> 7) & 0xFF;
            if (e >= 0x90) hits++;   // |v| >= 2^17: impossible for N(0,1) bf16 data
        }
        for (int off = 32; off; off >>= 1) hits += __shfl_down(hits, off);
        if (lane == 0) {
            flags[0] = (b == ~0ull) ? 1 : 0;
            flags[1] = (hits > 8) ? 1 : 0;
        }
    }
}

// ---------------------------------------------------------------- edge sort
__global__ void hist_kernel(const void* __restrict__ ei, int E, const int* __restrict__ flags,
                            int* __restrict__ deg) {
    int e = blockIdx.x * blockDim.x + threadIdx.x;
    if (e >= E) return;
    int d = flags[0] ? (int)((const long long*)ei)[(size_t)E + e]
                     : ((const int*)ei)[(size_t)E + e];
    atomicAdd(&deg[d], 1);
}

__global__ void scan_kernel(const int* __restrict__ deg, int* __restrict__ offs,
                            int* __restrict__ cursor) {
    __shared__ int part[256];
    int tid = threadIdx.x;
    int base = tid * 64;
    int s = 0;
    for (int i = 0; i < 64; ++i) s += deg[base + i];
    part[tid] = s;
    __syncthreads();
    for (int off = 1; off < 256; off <<= 1) {
        int t = (tid >= off) ? part[tid - off] : 0;
        __syncthreads();
        part[tid] += t;
        __syncthreads();
    }
    int run = (tid > 0) ? part[tid - 1] : 0;
    for (int i = 0; i < 64; ++i) {
        int idx = base + i;
        offs[idx] = run;
        cursor[idx] = run;
        run += deg[idx];
    }
    if (tid == 255) offs[NODES] = run;
}

__global__ void scatter_kernel(const void* __restrict__ ei, int E, const int* __restrict__ flags,
                               int* __restrict__ cursor, int* __restrict__ ssrc) {
    int e = blockIdx.x * blockDim.x + threadIdx.x;
    if (e >= E) return;
    int s, d;
    if (flags[0]) {
        const long long* p = (const long long*)ei;
        s = (int)p[e];
        d = (int)p[(size_t)E + e];
    } else {
        const int* p = (const int*)ei;
        s = p[e];
        d = p[(size_t)E + e];
    }
    int pos = atomicAdd(&cursor[d], 1);
    ssrc[pos] = s;
}

// ------------------------------------------- x0 staging + weight prep fused
#define T0 (NODES * K1PAD)
#define S1 (512 * K1PAD)
#define S2 (512 * 256)
__global__ void setup_kernel(const void* __restrict__ pooled, const void* __restrict__ rois,
                             const void* __restrict__ W1, const void* __restrict__ W2,
                             const void* __restrict__ W3, const int* __restrict__ flags,
                             unsigned short* __restrict__ x0p, void* __restrict__ outv,
                             unsigned short* __restrict__ wc1, unsigned short* __restrict__ wc2,
                             unsigned short* __restrict__ wc3) {
    int idx = blockIdx.x * 256 + threadIdx.x;
    bool f32m = flags[1] != 0;
    if (idx < T0) {
        int node = idx / K1PAD;
        int k = idx - node * K1PAD;
        float val = 0.f;
        if (k < 256) {
            val = f32m ? ((const float*)pooled)[(size_t)node * 256 + k]
                       : bf2f(((const unsigned short*)pooled)[(size_t)node * 256 + k]);
        } else if (k < D0) {
            val = f32m ? ((const float*)rois)[(size_t)node * 7 + (k - 256)]
                       : bf2f(((const unsigned short*)rois)[(size_t)node * 7 + (k - 256)]);
        }
        x0p[idx] = f2bf(val);
        if (k < D0) {
            if (f32m) ((float*)outv)[(size_t)node * OUTW + k] = val;
            else      ((unsigned short*)outv)[(size_t)node * OUTW + k] = f2bf(val);
        }
        return;
    }
    idx -= T0;
    if (idx < S1) {
        // layer 1: W1 is [256][526], in=263 padded to 288
        int r = idx / K1PAD;
        int k = idx - r * K1PAD;
        unsigned short val = 0;
        if (k < D0) {
            if (r < 256) {
                float a = f32m ? ((const float*)W1)[(size_t)r * 526 + k]
                               : bf2f(((const unsigned short*)W1)[(size_t)r * 526 + k]);
                val = f2bf(a);
            } else {
                size_t ro = (size_t)(r - 256) * 526;
                float a, b;
                if (f32m) { a = ((const float*)W1)[ro + k]; b = ((const float*)W1)[ro + D0 + k]; }
                else      { a = bf2f(((const unsigned short*)W1)[ro + k]);
                            b = bf2f(((const unsigned short*)W1)[ro + D0 + k]); }
                val = f2bf(b - a);
            }
        }
        wc1[idx] = val;
        return;
    }
    idx -= S1;
    const void* W = (idx < S2) ? W2 : W3;
    unsigned short* wc = (idx < S2) ? wc2 : wc3;
    if (idx >= S2) idx -= S2;
    int r = idx >> 8;
    int k = idx & 255;
    unsigned short val;
    if (r < 256) {
        float a = f32m ? ((const float*)W)[(size_t)r * 512 + k]
                       : bf2f(((const unsigned short*)W)[(size_t)r * 512 + k]);
        val = f2bf(a);
    } else {
        size_t ro = (size_t)(r - 256) * 512;
        float a, b;
        if (f32m) { a = ((const float*)W)[ro + k]; b = ((const float*)W)[ro + 256 + k]; }
        else      { a = bf2f(((const unsigned short*)W)[ro + k]);
                    b = bf2f(((const unsigned short*)W)[ro + 256 + k]); }
        val = f2bf(b - a);
    }
    wc[idx] = val;
}

// ---------------------------------------------------------------- GEMM
// T[M,512] = A[M,K] * Wc[512,K]^T ; cols 0..255 -> u as u16 KEYS, 256..511 -> v f32
// wave = 64 rows x 64 cols (acc[4][4]); block = 4 waves = 64 rows x 256 cols.
// grid (NODES/64, 2): blockIdx.y==0 -> u half, ==1 -> v half.
template <int K>
__global__ __launch_bounds__(256) void gemm_kernel(const unsigned short* __restrict__ A,
                                                   const unsigned short* __restrict__ Wc,
                                                   unsigned short* __restrict__ u_key,
                                                   float* __restrict__ v_f) {
    int lane = threadIdx.x & 63;
    int wave = threadIdx.x >> 6;
    int row0 = blockIdx.x * 64;
    int col0 = blockIdx.y * 256 + wave * 64;
    int lr = lane & 15;
    int kb = (lane >> 4) * 8;
    const unsigned short* Ap = A + (size_t)(row0 + lr) * K + kb;
    const unsigned short* Wp = Wc + (size_t)(col0 + lr) * K + kb;

    f32x4 acc[4][4];
    #pragma unroll
    for (int i = 0; i < 4; ++i)
        #pragma unroll
        for (int j = 0; j < 4; ++j) acc[i][j] = (f32x4){0.f, 0.f, 0.f, 0.f};

    for (int k0 = 0; k0 < K; k0 += 32) {
        bf16x8 a[4], b[4];
        #pragma unroll
        for (int i = 0; i < 4; ++i) a[i] = *reinterpret_cast<const bf16x8*>(Ap + (size_t)i * 16 * K + k0);
        #pragma unroll
        for (int i = 0; i < 4; ++i) b[i] = *reinterpret_cast<const bf16x8*>(Wp + (size_t)i * 16 * K + k0);
        #pragma unroll
        for (int rb = 0; rb < 4; ++rb)
            #pragma unroll
            for (int cb = 0; cb < 4; ++cb)
                acc[rb][cb] = __builtin_amdgcn_mfma_f32_16x16x32_bf16(a[rb], b[cb], acc[rb][cb], 0, 0, 0);
    }

    bool is_u = (blockIdx.y == 0);
    #pragma unroll
    for (int rb = 0; rb < 4; ++rb) {
        int rbase = row0 + rb * 16 + (lane >> 4) * 4;
        #pragma unroll
        for (int cb = 0; cb < 4; ++cb) {
            int c = col0 + cb * 16 + lr;
            #pragma unroll
            for (int reg = 0; reg < 4; ++reg) {
                float val = acc[rb][cb][reg];
                int r = rbase + reg;
                if (is_u) u_key[(size_t)r * 256 + c] = bf2key(f2bf(val));
                else      v_f[(size_t)r * 256 + (c - 256)] = val;
            }
        }
    }
}

// ---------------------------------------------------------------- combine
// one wave per node; two 32-lane halves own alternate sorted rows, uint4
// (8 key-ch) loads, 4 rows/half in flight, packed v_pk_max_u16 accumulate;
// cross-half shfl_xor merge; key->bf16 inversion only in epilogue.
__global__ __launch_bounds__(256) void combine_kernel(const unsigned short* __restrict__ u_key,
                                                      const float* __restrict__ v_f,
                                                      const void* __restrict__ bias,
                                                      const int* __restrict__ flags,
                                                      const int* __restrict__ offs,
                                                      const int* __restrict__ ssrc,
                                                      unsigned short* __restrict__ x_cur,
                                                      void* __restrict__ outv,
                                                      int col_off) {
    int lane = threadIdx.x & 63;
    int node = blockIdx.x * 4 + (threadIdx.x >> 6);
    int half = lane >> 5;      // 0/1: alternate rows
    int cl = lane & 31;        // channel-lane: ch cl*8 .. cl*8+7
    int s0 = offs[node];
    int s1 = offs[node + 1];
    bool f32m = flags[1] != 0;

    const u16x8* U = (const u16x8*)u_key;   // one row = 32 u16x8
    u16x8 mk = (u16x8)0;

    int i = s0 + half;
    for (; i + 6 < s1; i += 8) {
        int sA = ssrc[i], sB = ssrc[i + 2], sC = ssrc[i + 4], sD = ssrc[i + 6];
        u16x8 pA = U[(size_t)sA * 32 + cl];
        u16x8 pB = U[(size_t)sB * 32 + cl];
        u16x8 pC = U[(size_t)sC * 32 + cl];
        u16x8 pD = U[(size_t)sD * 32 + cl];
        mk = __builtin_elementwise_max(mk, __builtin_elementwise_max(
                 __builtin_elementwise_max(pA, pB), __builtin_elementwise_max(pC, pD)));
    }
    for (; i < s1; i += 2) {
        int s = ssrc[i];
        mk = __builtin_elementwise_max(mk, U[(size_t)s * 32 + cl]);
    }

    // merge halves: lanes l and l^32 hold the same channel group
    union { u16x8 v; uint4 u; } cvt;
    cvt.v = mk;
    cvt.u.x = __shfl_xor((int)cvt.u.x, 32);
    cvt.u.y = __shfl_xor((int)cvt.u.y, 32);
    cvt.u.z = __shfl_xor((int)cvt.u.z, 32);
    cvt.u.w = __shfl_xor((int)cvt.u.w, 32);
    mk = __builtin_elementwise_max(mk, cvt.v);

    // epilogue: lane handles 4 channels: ch0 = cl*8 + half*4
    int ch0 = cl * 8 + half * 4;
    float mm[4];
    #pragma unroll
    for (int j = 0; j < 4; ++j) mm[j] = bf2f(key2bf(mk[half * 4 + j]));

    float4 v = *(const float4*)(v_f + (size_t)node * 256 + ch0);
    float bb[4];
    if (f32m) {
        const float* bf = (const float*)bias;
        #pragma unroll
        for (int j = 0; j < 4; ++j) bb[j] = bf[ch0 + j];
    } else {
        const unsigned short* bh = (const unsigned short*)bias;
        #pragma unroll
        for (int j = 0; j < 4; ++j) bb[j] = bf2f(bh[ch0 + j]);
    }
    float vv[4] = {v.x, v.y, v.z, v.w};
    float r[4];
    bool nz = (s1 > s0);
    #pragma unroll
    for (int j = 0; j < 4; ++j) r[j] = nz ? fmaxf(mm[j] + vv[j] + bb[j], 0.f) : 0.f;

    unsigned short h[4];
    #pragma unroll
    for (int j = 0; j < 4; ++j) h[j] = f2bf(r[j]);
    uint2 packed;
    packed.x = (unsigned int)h[0] | ((unsigned int)h[1] << 16);
    packed.y = (unsigned int)h[2] | ((unsigned int)h[3] << 16);
    *(uint2*)(x_cur + (size_t)node * 256 + ch0) = packed;

    size_t ob = (size_t)node * OUTW + col_off + ch0;
    if (f32m) {
        float* of = (float*)outv;
        #pragma unroll
        for (int j = 0; j < 4; ++j) of[ob + j] = r[j];
    } else {
        unsigned short* oh = (unsigned short*)outv;
        #pragma unroll
        for (int j = 0; j < 4; ++j) oh[ob + j] = h[j];
    }
}

// ---------------------------------------------------------------- launch
extern "C" void kernel_launch(void* const* d_in, const int* in_sizes, int n_in,
                              void* d_out, int out_size, void* d_ws, size_t ws_size,
                              hipStream_t stream) {
    const void* rois   = d_in[0];
    const void* pooled = d_in[1];
    const void* ei     = d_in[2];
    const void* W1 = d_in[3];
    const void* b1 = d_in[4];
    const void* W2 = d_in[5];
    const void* b2 = d_in[6];
    const void* W3 = d_in[7];
    const void* b3 = d_in[8];

    const int E = in_sizes[2] / 2;

    char* ws = (char*)d_ws;
    size_t o = 0;
    auto take = [&](size_t bytes) { size_t cur = o; o += (bytes + 255) & ~(size_t)255; return cur; };
    int* flags           = (int*)(ws + take(8));
    int* deg             = (int*)(ws + take(sizeof(int) * NODES));
    int* offs            = (int*)(ws + take(sizeof(int) * (NODES + 1)));
    int* cursor          = (int*)(ws + take(sizeof(int) * NODES));
    int* ssrc            = (int*)(ws + take(sizeof(int) * (size_t)E));
    unsigned short* x0p  = (unsigned short*)(ws + take(2ull * NODES * K1PAD));
    unsigned short* wc1  = (unsigned short*)(ws + take(2ull * 512 * K1PAD));
    unsigned short* wc2  = (unsigned short*)(ws + take(2ull * 512 * 256));
    unsigned short* wc3  = (unsigned short*)(ws + take(2ull * 512 * 256));
    unsigned short* ukey = (unsigned short*)(ws + take(2ull * NODES * 256));
    float*          vf   = (float*)(ws + take(4ull * NODES * 256));
    unsigned short* xcur = (unsigned short*)(ws + take(2ull * NODES * 256));
    (void)ws_size;

    const int eb = (E + 255) / 256;

    detect_zero_kernel<<<NODES / 256, 256, 0, stream>>>(ei, pooled, flags, deg);
    hist_kernel<<<eb, 256, 0, stream>>>(ei, E, flags, deg);
    scan_kernel<<<1, 256, 0, stream>>>(deg, offs, cursor);
    scatter_kernel<<<eb, 256, 0, stream>>>(ei, E, flags, cursor, ssrc);

    setup_kernel<<<(T0 + S1 + 2 * S2) / 256, 256, 0, stream>>>(pooled, rois, W1, W2, W3, flags,
                                                               x0p, d_out, wc1, wc2, wc3);

    // layer 1
    gemm_kernel<K1PAD><<<dim3(NODES / 64, 2), 256, 0, stream>>>(x0p, wc1, ukey, vf);
    combine_kernel<<<NODES / 4, 256, 0, stream>>>(ukey, vf, b1, flags, offs, ssrc, xcur, d_out, D0);

    // layer 2
    gemm_kernel<256><<<dim3(NODES / 64, 2), 256, 0, stream>>>(xcur, wc2, ukey, vf);
    combine_kernel<<<NODES / 4, 256, 0, stream>>>(ukey, vf, b2, flags, offs, ssrc, xcur, d_out, D0 + 256);

    // layer 3
    gemm_kernel<256><<<dim3(NODES / 64, 2), 256, 0, stream>>>(xcur, wc3, ukey, vf);
    combine_kernel<<<NODES / 4, 256, 0, stream>>>(ukey, vf, b3, flags, offs, ssrc, xcur, d_out, D0 + 512);
}